// Round 7
// baseline (493.011 us; speedup 1.0000x reference)
//
#include <hip/hip_runtime.h>

// AttentionBlock: x[4,2048,1024] fp32; scores = x@(Wq@Wk^T)@x^T (NO scale);
// softmax; out = P@(x@Wv).
// M' = Wk@Wq^T -> y = x@M'^T replaces both q,k projections; scores = y@x^T.
// Split-f16 (hi+lo, 3-MFMA) for M', y, scores; plain f16 for v, PV.
// Round 7: revert to round-3 16x16x32 / 128x128 / 256-thr structure (best
// measured) + drain-halving experiment in gemm_split: hi planes via
// global_load_lds DMA (4 insts -> half the vmcnt(0) barrier drain, 16 KB LDS),
// lo fragments loaded directly global->VGPR (L2-resident, latency hidden
// under the hi MFMAs).

typedef _Float16 half4_t __attribute__((ext_vector_type(4)));
typedef _Float16 half8_t __attribute__((ext_vector_type(8)));
typedef float f32x4 __attribute__((ext_vector_type(4)));

#define BM 128
#define BN 128
#define BK 32

__device__ __forceinline__ void gl_lds16(const _Float16* g, _Float16* l) {
    __builtin_amdgcn_global_load_lds(
        (const __attribute__((address_space(1))) unsigned int*)g,
        (__attribute__((address_space(3))) unsigned int*)l, 16, 0, 0);
}

// ---------------- merged conversion kernel ----------------
// role (blockIdx.y): 0 = x split (2M float4), 1 = wq split, 2 = wk split,
// 3 = wv -> wvT f16 hi (256 tile-blocks of 64x64).
__global__ __launch_bounds__(256) void conv_all_kernel(
    const float* __restrict__ x, const float* __restrict__ wq,
    const float* __restrict__ wk, const float* __restrict__ wv,
    _Float16* __restrict__ xh, _Float16* __restrict__ xl,
    _Float16* __restrict__ qh, _Float16* __restrict__ ql,
    _Float16* __restrict__ kh, _Float16* __restrict__ kl,
    _Float16* __restrict__ vTh)
{
    __shared__ float tle[64][65];
    const int role = blockIdx.y;
    if (role < 3) {
        const float* in = (role == 0) ? x : (role == 1) ? wq : wk;
        _Float16* hi = (role == 0) ? xh : (role == 1) ? qh : kh;
        _Float16* lo = (role == 0) ? xl : (role == 1) ? ql : kl;
        const int n4 = (role == 0) ? (1 << 21) : (1 << 18);
        int i = blockIdx.x * 256 + threadIdx.x;
        if (i >= n4) return;
        float4 v = ((const float4*)in)[i];
        float xs[4] = {v.x, v.y, v.z, v.w};
        half4_t h, l;
#pragma unroll
        for (int j = 0; j < 4; ++j) {
            _Float16 hh = (_Float16)xs[j];
            h[j] = hh;
            l[j] = (_Float16)(xs[j] - (float)hh);
        }
        ((half4_t*)hi)[i] = h;
        ((half4_t*)lo)[i] = l;
    } else {
        if (blockIdx.x >= 256) return;
        const int tr = (blockIdx.x >> 4) * 64, tc = (blockIdx.x & 15) * 64;
        const int t16 = threadIdx.x & 15, tq = threadIdx.x >> 4;
#pragma unroll
        for (int j = 0; j < 4; ++j) {
            int lr = tq + j * 16;
            float4 v = *(const float4*)(wv + (size_t)(tr + lr) * 1024 + tc + t16 * 4);
            tle[lr][t16 * 4 + 0] = v.x;
            tle[lr][t16 * 4 + 1] = v.y;
            tle[lr][t16 * 4 + 2] = v.z;
            tle[lr][t16 * 4 + 3] = v.w;
        }
        __syncthreads();
#pragma unroll
        for (int j = 0; j < 4; ++j) {
            int orow = tq + j * 16;
            int oc = t16 * 4;
            half4_t h;
#pragma unroll
            for (int i = 0; i < 4; ++i) h[i] = (_Float16)tle[oc + i][orow];
            *(half4_t*)(vTh + (size_t)(tc + orow) * 1024 + tr + oc) = h;
        }
    }
}

// ---------------- split-f16 GEMM (3-MFMA, 16x16x32), 128x128, 256 thr ----------------
// A planes [M][K] f16, B planes [N][K] f16 (k-contiguous both).
// hi planes staged via global_load_lds; lo fragments loaded direct to VGPR.
// OUTF32: write fp32 C. else: write f16 hi/lo pair.
template <bool OUTF32>
__global__ __launch_bounds__(256) void gemm_split(
    const _Float16* __restrict__ Ah, const _Float16* __restrict__ Al, size_t az,
    const _Float16* __restrict__ Bh, const _Float16* __restrict__ Bl, size_t bz,
    float* __restrict__ Cf, size_t cz, int ldc,
    _Float16* __restrict__ Oh, _Float16* __restrict__ Ol, size_t oz, int ldo,
    int lda, int ldb, int K)
{
    __shared__ __align__(16) _Float16 sAh[BM][BK];
    __shared__ __align__(16) _Float16 sBh[BN][BK];

    const int tid = threadIdx.x;
    const int wave = tid >> 6, lane = tid & 63;
    const int wm = (wave >> 1) * 64, wn = (wave & 1) * 64;  // 2x2 waves, 64x64 each
    const int lrow = lane & 15, quad = lane >> 4;
    const int bm = blockIdx.y * BM, bn = blockIdx.x * BN;
    const int z = blockIdx.z;

    const _Float16* pAh = Ah + (size_t)z * az;
    const _Float16* pAl = Al + (size_t)z * az;
    const _Float16* pBh = Bh + (size_t)z * bz;
    const _Float16* pBl = Bl + (size_t)z * bz;

    // hi staging (round-3 proven): wave w covers rows [32w,32w+32); lane covers
    // row 32w + lane/4 (+16), k-offset (lane&3)*8; LDS dest = base + 16*lane B.
    const int r0 = wave * 32 + (lane >> 2);
    const int kofs = (lane & 3) * 8;
    const size_t a0o = (size_t)(bm + r0) * lda + kofs;
    const size_t a1o = a0o + (size_t)16 * lda;
    const size_t b0o = (size_t)(bn + r0) * ldb + kofs;
    const size_t b1o = b0o + (size_t)16 * ldb;
    _Float16* lA0 = &sAh[r0][kofs];
    _Float16* lA1 = &sAh[r0 + 16][kofs];
    _Float16* lB0 = &sBh[r0][kofs];
    _Float16* lB1 = &sBh[r0 + 16][kofs];

    // direct lo fragment base offsets (per-lane, MFMA A/B layout:
    // row = base + mt*16 + lrow, k-chunk = quad*8)
    const size_t alo = (size_t)(bm + wm + lrow) * lda + quad * 8;
    const size_t blo = (size_t)(bn + wn + lrow) * ldb + quad * 8;

    f32x4 acc[4][4];
#pragma unroll
    for (int i = 0; i < 4; ++i)
#pragma unroll
        for (int j = 0; j < 4; ++j) acc[i][j] = 0.0f;

    for (int k0 = 0; k0 < K; k0 += BK) {
        // hi-plane DMA (the only loads the barrier must drain)
        gl_lds16(pAh + a0o + k0, lA0);
        gl_lds16(pAh + a1o + k0, lA1);
        gl_lds16(pBh + b0o + k0, lB0);
        gl_lds16(pBh + b1o + k0, lB1);

        // lo fragments direct to VGPR (issued before barrier; latency hides
        // under the hi*hi MFMAs; L2-resident due to cross-block reuse)
        half8_t aL[4], bL[4];
#pragma unroll
        for (int mt = 0; mt < 4; ++mt)
            aL[mt] = *(const half8_t*)(pAl + alo + (size_t)mt * 16 * lda + k0);
#pragma unroll
        for (int nt = 0; nt < 4; ++nt)
            bL[nt] = *(const half8_t*)(pBl + blo + (size_t)nt * 16 * ldb + k0);

        __syncthreads();

        half8_t aH[4], bH[4];
#pragma unroll
        for (int mt = 0; mt < 4; ++mt)
            aH[mt] = *(const half8_t*)&sAh[wm + mt * 16 + lrow][quad * 8];
#pragma unroll
        for (int nt = 0; nt < 4; ++nt)
            bH[nt] = *(const half8_t*)&sBh[wn + nt * 16 + lrow][quad * 8];

#pragma unroll
        for (int mt = 0; mt < 4; ++mt)
#pragma unroll
            for (int nt = 0; nt < 4; ++nt)
                acc[mt][nt] = __builtin_amdgcn_mfma_f32_16x16x32_f16(aH[mt], bH[nt], acc[mt][nt], 0, 0, 0);
#pragma unroll
        for (int mt = 0; mt < 4; ++mt)
#pragma unroll
            for (int nt = 0; nt < 4; ++nt)
                acc[mt][nt] = __builtin_amdgcn_mfma_f32_16x16x32_f16(aH[mt], bL[nt], acc[mt][nt], 0, 0, 0);
#pragma unroll
        for (int mt = 0; mt < 4; ++mt)
#pragma unroll
            for (int nt = 0; nt < 4; ++nt)
                acc[mt][nt] = __builtin_amdgcn_mfma_f32_16x16x32_f16(aL[mt], bH[nt], acc[mt][nt], 0, 0, 0);
        __syncthreads();
    }

    // epilogue: C/D layout col=lane&15, row=quad*4+r
#pragma unroll
    for (int mt = 0; mt < 4; ++mt)
#pragma unroll
        for (int nt = 0; nt < 4; ++nt)
#pragma unroll
            for (int r = 0; r < 4; ++r) {
                int gm = bm + wm + mt * 16 + quad * 4 + r;
                int gn = bn + wn + nt * 16 + lrow;
                float v = acc[mt][nt][r];
                if (OUTF32) {
                    Cf[(size_t)z * cz + (size_t)gm * ldc + gn] = v;
                } else {
                    _Float16 h = (_Float16)v;
                    Oh[(size_t)z * oz + (size_t)gm * ldo + gn] = h;
                    Ol[(size_t)z * oz + (size_t)gm * ldo + gn] = (_Float16)(v - (float)h);
                }
            }
}

// ---------------- plain-f16 GEMM (16x16x32), 128x128, 256 thr (round-3) ----------------
// A [M][K] f16, B [N][K] f16. TRANSOUT: write f16 C^T per-batch as
// vT[b][n][t] (b = gm>>11, t = gm&2047); else write fp32 C row-major.
template <bool TRANSOUT>
__global__ __launch_bounds__(256) void gemm_plain(
    const _Float16* __restrict__ Ag, size_t az,
    const _Float16* __restrict__ Bg, size_t bz,
    float* __restrict__ Cf, size_t cz, int ldc,
    _Float16* __restrict__ Ot,
    int lda, int ldb, int K)
{
    __shared__ __align__(16) _Float16 sA[BM][BK], sB[BN][BK];

    const int tid = threadIdx.x;
    const int wave = tid >> 6, lane = tid & 63;
    const int wm = (wave >> 1) * 64, wn = (wave & 1) * 64;
    const int lrow = lane & 15, quad = lane >> 4;
    const int bm = blockIdx.y * BM, bn = blockIdx.x * BN;
    const int z = blockIdx.z;

    const _Float16* pA = Ag + (size_t)z * az;
    const _Float16* pB = Bg + (size_t)z * bz;

    const int r0 = wave * 32 + (lane >> 2);
    const int kofs = (lane & 3) * 8;
    const size_t a0o = (size_t)(bm + r0) * lda + kofs;
    const size_t a1o = a0o + (size_t)16 * lda;
    const size_t b0o = (size_t)(bn + r0) * ldb + kofs;
    const size_t b1o = b0o + (size_t)16 * ldb;
    _Float16* lA0 = &sA[r0][kofs];
    _Float16* lA1 = &sA[r0 + 16][kofs];
    _Float16* lB0 = &sB[r0][kofs];
    _Float16* lB1 = &sB[r0 + 16][kofs];

    f32x4 acc[4][4];
#pragma unroll
    for (int i = 0; i < 4; ++i)
#pragma unroll
        for (int j = 0; j < 4; ++j) acc[i][j] = 0.0f;

    for (int k0 = 0; k0 < K; k0 += BK) {
        gl_lds16(pA + a0o + k0, lA0);
        gl_lds16(pA + a1o + k0, lA1);
        gl_lds16(pB + b0o + k0, lB0);
        gl_lds16(pB + b1o + k0, lB1);
        __syncthreads();

        half8_t a0[4], b0[4];
#pragma unroll
        for (int mt = 0; mt < 4; ++mt)
            a0[mt] = *(const half8_t*)&sA[wm + mt * 16 + lrow][quad * 8];
#pragma unroll
        for (int nt = 0; nt < 4; ++nt)
            b0[nt] = *(const half8_t*)&sB[wn + nt * 16 + lrow][quad * 8];
#pragma unroll
        for (int mt = 0; mt < 4; ++mt)
#pragma unroll
            for (int nt = 0; nt < 4; ++nt)
                acc[mt][nt] = __builtin_amdgcn_mfma_f32_16x16x32_f16(a0[mt], b0[nt], acc[mt][nt], 0, 0, 0);
        __syncthreads();
    }

#pragma unroll
    for (int mt = 0; mt < 4; ++mt)
#pragma unroll
        for (int nt = 0; nt < 4; ++nt) {
            int gm0 = bm + wm + mt * 16 + quad * 4;
            int gn = bn + wn + nt * 16 + lrow;
            if (TRANSOUT) {
                half4_t o;
#pragma unroll
                for (int r = 0; r < 4; ++r) o[r] = (_Float16)acc[mt][nt][r];
                *(half4_t*)(Ot + ((size_t)(gm0 >> 11) << 21) +
                            (size_t)gn * 2048 + (gm0 & 2047)) = o;
            } else {
#pragma unroll
                for (int r = 0; r < 4; ++r)
                    Cf[(size_t)z * cz + (size_t)(gm0 + r) * ldc + gn] = acc[mt][nt][r];
            }
        }
}

// ---------------- softmax: fp32 scores row -> f16 P row, in place ----------------
__global__ __launch_bounds__(256) void softmax_kernel(float* __restrict__ S)
{
    float* row = S + (size_t)blockIdx.x * 2048;
    float4* r4 = (float4*)row;
    const int tid = threadIdx.x;
    const int wave = tid >> 6, lane = tid & 63;

    float4 a = r4[tid], b = r4[tid + 256];
    float m = fmaxf(fmaxf(fmaxf(a.x, a.y), fmaxf(a.z, a.w)),
                    fmaxf(fmaxf(b.x, b.y), fmaxf(b.z, b.w)));
#pragma unroll
    for (int o = 32; o; o >>= 1) m = fmaxf(m, __shfl_xor(m, o));
    __shared__ float redm[4];
    __shared__ float reds[4];
    if (lane == 0) redm[wave] = m;
    __syncthreads();
    m = fmaxf(fmaxf(redm[0], redm[1]), fmaxf(redm[2], redm[3]));

    a.x = __expf(a.x - m); a.y = __expf(a.y - m);
    a.z = __expf(a.z - m); a.w = __expf(a.w - m);
    b.x = __expf(b.x - m); b.y = __expf(b.y - m);
    b.z = __expf(b.z - m); b.w = __expf(b.w - m);

    float s = a.x + a.y + a.z + a.w + b.x + b.y + b.z + b.w;
#pragma unroll
    for (int o = 32; o; o >>= 1) s += __shfl_xor(s, o);
    if (lane == 0) reds[wave] = s;
    __syncthreads();   // also orders all row loads before the f16 overwrite below
    s = reds[0] + reds[1] + reds[2] + reds[3];

    float inv = 1.0f / s;
    _Float16* o16 = (_Float16*)row;
    half4_t ha, hb;
    ha[0] = (_Float16)(a.x * inv); ha[1] = (_Float16)(a.y * inv);
    ha[2] = (_Float16)(a.z * inv); ha[3] = (_Float16)(a.w * inv);
    hb[0] = (_Float16)(b.x * inv); hb[1] = (_Float16)(b.y * inv);
    hb[2] = (_Float16)(b.z * inv); hb[3] = (_Float16)(b.w * inv);
    ((half4_t*)o16)[tid] = ha;
    ((half4_t*)o16)[tid + 256] = hb;
}

extern "C" void kernel_launch(void* const* d_in, const int* in_sizes, int n_in,
                              void* d_out, int out_size, void* d_ws, size_t ws_size,
                              hipStream_t stream)
{
    const float* x  = (const float*)d_in[0];
    const float* wq = (const float*)d_in[1];
    const float* wk = (const float*)d_in[2];
    const float* wv = (const float*)d_in[3];
    float* out = (float*)d_out;

    const int S = 2048, D = 1024;
    char* ws = (char*)d_ws;

    // ws layout (bytes); high-water 158 MB
    _Float16* xh   = (_Float16*)(ws);                  // 16 MB
    _Float16* xl   = (_Float16*)(ws + (16ull << 20));  // 16 MB
    _Float16* yh   = (_Float16*)(ws + (32ull << 20));  // 16 MB
    _Float16* yl   = (_Float16*)(ws + (48ull << 20));  // 16 MB
    _Float16* vT   = (_Float16*)(ws + (64ull << 20));  // 16 MB [4][1024][2048]
    _Float16* wqh  = (_Float16*)(ws + (80ull << 20));  // 2 MB (natural layout)
    _Float16* wql  = (_Float16*)(ws + (82ull << 20));  // 2 MB
    _Float16* wkh  = (_Float16*)(ws + (84ull << 20));  // 2 MB
    _Float16* wkl  = (_Float16*)(ws + (86ull << 20));  // 2 MB
    _Float16* wvTh = (_Float16*)(ws + (88ull << 20));  // 2 MB (transposed)
    _Float16* Mh   = (_Float16*)(ws + (90ull << 20));  // 2 MB  M' = Wk@Wq^T
    _Float16* Ml   = (_Float16*)(ws + (92ull << 20));  // 2 MB
    float*    sc   = (float*)(ws + (94ull << 20));     // 64 MB scores

    // 1) all conversions in one launch
    conv_all_kernel<<<dim3(8192, 4), dim3(256), 0, stream>>>(
        x, wq, wk, wv, xh, xl, wqh, wql, wkh, wkl, wvTh);

    // 2) M'[d'][d] = sum_e Wk[d',e]*Wq[d,e]  (split in, split out)
    gemm_split<false><<<dim3(D / BN, D / BM, 1), dim3(256), 0, stream>>>(
        wkh, wkl, 0, wqh, wql, 0, nullptr, 0, 0, Mh, Ml, 0, D, D, D, D);

    // 3) y[s][d'] = sum_d x[s,d]*M'[d',d]  (split in, split out)
    gemm_split<false><<<dim3(D / BN, 8192 / BM, 1), dim3(256), 0, stream>>>(
        xh, xl, 0, Mh, Ml, 0, nullptr, 0, 0, yh, yl, 0, D, D, D, D);

    // 4) v projection (plain f16), epilogue writes vT[b][d][t] f16
    gemm_plain<true><<<dim3(D / BN, 8192 / BM, 1), dim3(256), 0, stream>>>(
        xh, 0, wvTh, 0, nullptr, 0, 0, vT, D, D, D);

    // 5) scores[b][s][t] = sum_d' y[b,s,d']*x[b,t,d']  (split), out fp32
    gemm_split<true><<<dim3(S / BN, S / BM, 4), dim3(256), 0, stream>>>(
        yh, yl, (size_t)S * D, xh, xl, (size_t)S * D, sc, (size_t)S * S, S,
        nullptr, nullptr, 0, 0, D, D, D);

    // 6) softmax rows, f16 P written in place (row stride stays 8192 B)
    softmax_kernel<<<dim3(4 * S), dim3(256), 0, stream>>>(sc);

    // 7) out = P @ v: A=P f16 (lda=4096 f16 elems), B=vT f16, out fp32
    gemm_plain<false><<<dim3(D / BN, S / BM, 4), dim3(256), 0, stream>>>(
        (const _Float16*)sc, (size_t)S * 4096, vT, (size_t)D * S,
        out, (size_t)S * D, D, nullptr, 4096, S, S);
}

// Round 8
// 414.294 us; speedup vs baseline: 1.1900x; 1.1900x over previous
//
#include <hip/hip_runtime.h>

// AttentionBlock: x[4,2048,1024] fp32; scores = x@(Wq@Wk^T)@x^T (NO scale);
// softmax; out = P@(x@Wv).
// M' = Wk@Wq^T -> y = x@M'^T replaces both q,k projections; scores = y@x^T.
// Split-f16 (hi+lo, 3-MFMA) for M', y, scores; plain f16 for v, PV.
// Round 8: exact round-3 GEMM structure (16x16x32, 128x128, 256thr, all-LDS
// staging — best measured; r4-r7 K-loop experiments all regressed). New:
// (a) y-proj + v-proj merged into one launch via blockIdx.z role,
// (b) v epilogue transposes through LDS -> coalesced 16B vT writes
//     (old path: 8B per lane at 4KB stride).

typedef _Float16 half4_t __attribute__((ext_vector_type(4)));
typedef _Float16 half8_t __attribute__((ext_vector_type(8)));
typedef float f32x4 __attribute__((ext_vector_type(4)));

#define BM 128
#define BN 128
#define BK 32

__device__ __forceinline__ void gl_lds16(const _Float16* g, _Float16* l) {
    __builtin_amdgcn_global_load_lds(
        (const __attribute__((address_space(1))) unsigned int*)g,
        (__attribute__((address_space(3))) unsigned int*)l, 16, 0, 0);
}

// ---------------- merged conversion kernel ----------------
// role (blockIdx.y): 0 = x split (2M float4), 1 = wq split, 2 = wk split,
// 3 = wv -> wvT f16 hi (256 tile-blocks of 64x64).
__global__ __launch_bounds__(256) void conv_all_kernel(
    const float* __restrict__ x, const float* __restrict__ wq,
    const float* __restrict__ wk, const float* __restrict__ wv,
    _Float16* __restrict__ xh, _Float16* __restrict__ xl,
    _Float16* __restrict__ qh, _Float16* __restrict__ ql,
    _Float16* __restrict__ kh, _Float16* __restrict__ kl,
    _Float16* __restrict__ vTh)
{
    __shared__ float tle[64][65];
    const int role = blockIdx.y;
    if (role < 3) {
        const float* in = (role == 0) ? x : (role == 1) ? wq : wk;
        _Float16* hi = (role == 0) ? xh : (role == 1) ? qh : kh;
        _Float16* lo = (role == 0) ? xl : (role == 1) ? ql : kl;
        const int n4 = (role == 0) ? (1 << 21) : (1 << 18);
        int i = blockIdx.x * 256 + threadIdx.x;
        if (i >= n4) return;
        float4 v = ((const float4*)in)[i];
        float xs[4] = {v.x, v.y, v.z, v.w};
        half4_t h, l;
#pragma unroll
        for (int j = 0; j < 4; ++j) {
            _Float16 hh = (_Float16)xs[j];
            h[j] = hh;
            l[j] = (_Float16)(xs[j] - (float)hh);
        }
        ((half4_t*)hi)[i] = h;
        ((half4_t*)lo)[i] = l;
    } else {
        if (blockIdx.x >= 256) return;
        const int tr = (blockIdx.x >> 4) * 64, tc = (blockIdx.x & 15) * 64;
        const int t16 = threadIdx.x & 15, tq = threadIdx.x >> 4;
#pragma unroll
        for (int j = 0; j < 4; ++j) {
            int lr = tq + j * 16;
            float4 v = *(const float4*)(wv + (size_t)(tr + lr) * 1024 + tc + t16 * 4);
            tle[lr][t16 * 4 + 0] = v.x;
            tle[lr][t16 * 4 + 1] = v.y;
            tle[lr][t16 * 4 + 2] = v.z;
            tle[lr][t16 * 4 + 3] = v.w;
        }
        __syncthreads();
#pragma unroll
        for (int j = 0; j < 4; ++j) {
            int orow = tq + j * 16;
            int oc = t16 * 4;
            half4_t h;
#pragma unroll
            for (int i = 0; i < 4; ++i) h[i] = (_Float16)tle[oc + i][orow];
            *(half4_t*)(vTh + (size_t)(tc + orow) * 1024 + tr + oc) = h;
        }
    }
}

// ---------------- split-f16 GEMM (3-MFMA, 16x16x32), 128x128, 256 thr ----------------
// Round-3 exact. A planes [M][K], B planes [N][K] f16 (k-contiguous both).
// OUTF32: write fp32 C. else: write f16 hi/lo pair.
template <bool OUTF32>
__global__ __launch_bounds__(256) void gemm_split(
    const _Float16* __restrict__ Ah, const _Float16* __restrict__ Al, size_t az,
    const _Float16* __restrict__ Bh, const _Float16* __restrict__ Bl, size_t bz,
    float* __restrict__ Cf, size_t cz, int ldc,
    _Float16* __restrict__ Oh, _Float16* __restrict__ Ol, size_t oz, int ldo,
    int lda, int ldb, int K)
{
    __shared__ __align__(16) _Float16 sAh[BM][BK], sAl[BM][BK];
    __shared__ __align__(16) _Float16 sBh[BN][BK], sBl[BN][BK];

    const int tid = threadIdx.x;
    const int wave = tid >> 6, lane = tid & 63;
    const int wm = (wave >> 1) * 64, wn = (wave & 1) * 64;
    const int lrow = lane & 15, quad = lane >> 4;
    const int bm = blockIdx.y * BM, bn = blockIdx.x * BN;
    const int z = blockIdx.z;

    const _Float16* pAh = Ah + (size_t)z * az;
    const _Float16* pAl = Al + (size_t)z * az;
    const _Float16* pBh = Bh + (size_t)z * bz;
    const _Float16* pBl = Bl + (size_t)z * bz;

    const int r0 = wave * 32 + (lane >> 2);
    const int kofs = (lane & 3) * 8;
    const size_t a0o = (size_t)(bm + r0) * lda + kofs;
    const size_t a1o = a0o + (size_t)16 * lda;
    const size_t b0o = (size_t)(bn + r0) * ldb + kofs;
    const size_t b1o = b0o + (size_t)16 * ldb;
    _Float16* lA0 = &sAh[r0][kofs];
    _Float16* lA1 = &sAh[r0 + 16][kofs];
    _Float16* lAl0 = &sAl[r0][kofs];
    _Float16* lAl1 = &sAl[r0 + 16][kofs];
    _Float16* lB0 = &sBh[r0][kofs];
    _Float16* lB1 = &sBh[r0 + 16][kofs];
    _Float16* lBl0 = &sBl[r0][kofs];
    _Float16* lBl1 = &sBl[r0 + 16][kofs];

    f32x4 acc[4][4];
#pragma unroll
    for (int i = 0; i < 4; ++i)
#pragma unroll
        for (int j = 0; j < 4; ++j) acc[i][j] = 0.0f;

    for (int k0 = 0; k0 < K; k0 += BK) {
        gl_lds16(pAh + a0o + k0, lA0);
        gl_lds16(pAh + a1o + k0, lA1);
        gl_lds16(pAl + a0o + k0, lAl0);
        gl_lds16(pAl + a1o + k0, lAl1);
        gl_lds16(pBh + b0o + k0, lB0);
        gl_lds16(pBh + b1o + k0, lB1);
        gl_lds16(pBl + b0o + k0, lBl0);
        gl_lds16(pBl + b1o + k0, lBl1);
        __syncthreads();

        half8_t a0[4], a1[4], b0[4], b1[4];
#pragma unroll
        for (int mt = 0; mt < 4; ++mt) {
            a0[mt] = *(const half8_t*)&sAh[wm + mt * 16 + lrow][quad * 8];
            a1[mt] = *(const half8_t*)&sAl[wm + mt * 16 + lrow][quad * 8];
        }
#pragma unroll
        for (int nt = 0; nt < 4; ++nt) {
            b0[nt] = *(const half8_t*)&sBh[wn + nt * 16 + lrow][quad * 8];
            b1[nt] = *(const half8_t*)&sBl[wn + nt * 16 + lrow][quad * 8];
        }
#pragma unroll
        for (int mt = 0; mt < 4; ++mt)
#pragma unroll
            for (int nt = 0; nt < 4; ++nt) {
                acc[mt][nt] = __builtin_amdgcn_mfma_f32_16x16x32_f16(a0[mt], b0[nt], acc[mt][nt], 0, 0, 0);
                acc[mt][nt] = __builtin_amdgcn_mfma_f32_16x16x32_f16(a0[mt], b1[nt], acc[mt][nt], 0, 0, 0);
                acc[mt][nt] = __builtin_amdgcn_mfma_f32_16x16x32_f16(a1[mt], b0[nt], acc[mt][nt], 0, 0, 0);
            }
        __syncthreads();
    }

#pragma unroll
    for (int mt = 0; mt < 4; ++mt)
#pragma unroll
        for (int nt = 0; nt < 4; ++nt)
#pragma unroll
            for (int r = 0; r < 4; ++r) {
                int gm = bm + wm + mt * 16 + quad * 4 + r;
                int gn = bn + wn + nt * 16 + lrow;
                float v = acc[mt][nt][r];
                if (OUTF32) {
                    Cf[(size_t)z * cz + (size_t)gm * ldc + gn] = v;
                } else {
                    _Float16 h = (_Float16)v;
                    Oh[(size_t)z * oz + (size_t)gm * ldo + gn] = h;
                    Ol[(size_t)z * oz + (size_t)gm * ldo + gn] = (_Float16)(v - (float)h);
                }
            }
}

// ---------------- merged y-proj (split) + v-proj (plain) kernel ----------------
// role = blockIdx.z. role 0: y[s][d'] = sum_d x[s,d]*M'[d',d], split-out to
// yh/yl. role 1: v[s][e] = sum_d x[s,d]*wvT[e,d], plain f16, epilogue writes
// vT[b][e][t] coalesced via LDS transpose. Fixed K=1024, ld*=1024.
__global__ __launch_bounds__(256) void yv_kernel(
    const _Float16* __restrict__ xh, const _Float16* __restrict__ xl,
    const _Float16* __restrict__ Mh, const _Float16* __restrict__ Ml,
    const _Float16* __restrict__ wvTh,
    _Float16* __restrict__ yh, _Float16* __restrict__ yl,
    _Float16* __restrict__ vT)
{
    __shared__ __align__(16) char buf[128 * 132 * 2];  // 33792 B

    const int tid = threadIdx.x;
    const int wave = tid >> 6, lane = tid & 63;
    const int wm = (wave >> 1) * 64, wn = (wave & 1) * 64;
    const int lrow = lane & 15, quad = lane >> 4;
    const int bm = blockIdx.y * BM, bn = blockIdx.x * BN;
    const bool vrole = (blockIdx.z != 0);

    const int r0 = wave * 32 + (lane >> 2);
    const int kofs = (lane & 3) * 8;
    const size_t a0o = (size_t)(bm + r0) * 1024 + kofs;
    const size_t a1o = a0o + (size_t)16 * 1024;
    const size_t b0o = (size_t)(bn + r0) * 1024 + kofs;
    const size_t b1o = b0o + (size_t)16 * 1024;

    f32x4 acc[4][4];
#pragma unroll
    for (int i = 0; i < 4; ++i)
#pragma unroll
        for (int j = 0; j < 4; ++j) acc[i][j] = 0.0f;

    if (!vrole) {
        // ---- split path: A = xh/xl, B = Mh/Ml
        _Float16* sAh = (_Float16*)buf;               // [128][32]
        _Float16* sAl = (_Float16*)(buf + 8192);
        _Float16* sBh = (_Float16*)(buf + 16384);
        _Float16* sBl = (_Float16*)(buf + 24576);
        _Float16* lA0 = sAh + r0 * BK + kofs;
        _Float16* lA1 = sAh + (r0 + 16) * BK + kofs;
        _Float16* lAl0 = sAl + r0 * BK + kofs;
        _Float16* lAl1 = sAl + (r0 + 16) * BK + kofs;
        _Float16* lB0 = sBh + r0 * BK + kofs;
        _Float16* lB1 = sBh + (r0 + 16) * BK + kofs;
        _Float16* lBl0 = sBl + r0 * BK + kofs;
        _Float16* lBl1 = sBl + (r0 + 16) * BK + kofs;

        for (int k0 = 0; k0 < 1024; k0 += BK) {
            gl_lds16(xh + a0o + k0, lA0);
            gl_lds16(xh + a1o + k0, lA1);
            gl_lds16(xl + a0o + k0, lAl0);
            gl_lds16(xl + a1o + k0, lAl1);
            gl_lds16(Mh + b0o + k0, lB0);
            gl_lds16(Mh + b1o + k0, lB1);
            gl_lds16(Ml + b0o + k0, lBl0);
            gl_lds16(Ml + b1o + k0, lBl1);
            __syncthreads();

            half8_t a0[4], a1[4], b0[4], b1[4];
#pragma unroll
            for (int mt = 0; mt < 4; ++mt) {
                a0[mt] = *(const half8_t*)(sAh + (wm + mt * 16 + lrow) * BK + quad * 8);
                a1[mt] = *(const half8_t*)(sAl + (wm + mt * 16 + lrow) * BK + quad * 8);
            }
#pragma unroll
            for (int nt = 0; nt < 4; ++nt) {
                b0[nt] = *(const half8_t*)(sBh + (wn + nt * 16 + lrow) * BK + quad * 8);
                b1[nt] = *(const half8_t*)(sBl + (wn + nt * 16 + lrow) * BK + quad * 8);
            }
#pragma unroll
            for (int mt = 0; mt < 4; ++mt)
#pragma unroll
                for (int nt = 0; nt < 4; ++nt) {
                    acc[mt][nt] = __builtin_amdgcn_mfma_f32_16x16x32_f16(a0[mt], b0[nt], acc[mt][nt], 0, 0, 0);
                    acc[mt][nt] = __builtin_amdgcn_mfma_f32_16x16x32_f16(a0[mt], b1[nt], acc[mt][nt], 0, 0, 0);
                    acc[mt][nt] = __builtin_amdgcn_mfma_f32_16x16x32_f16(a1[mt], b0[nt], acc[mt][nt], 0, 0, 0);
                }
            __syncthreads();
        }

#pragma unroll
        for (int mt = 0; mt < 4; ++mt)
#pragma unroll
            for (int nt = 0; nt < 4; ++nt)
#pragma unroll
                for (int r = 0; r < 4; ++r) {
                    int gm = bm + wm + mt * 16 + quad * 4 + r;
                    int gn = bn + wn + nt * 16 + lrow;
                    float v = acc[mt][nt][r];
                    _Float16 h = (_Float16)v;
                    yh[(size_t)gm * 1024 + gn] = h;
                    yl[(size_t)gm * 1024 + gn] = (_Float16)(v - (float)h);
                }
    } else {
        // ---- plain path: A = xh, B = wvTh
        _Float16* sA = (_Float16*)buf;     // [128][32]
        _Float16* sB = (_Float16*)(buf + 8192);
        _Float16* lA0 = sA + r0 * BK + kofs;
        _Float16* lA1 = sA + (r0 + 16) * BK + kofs;
        _Float16* lB0 = sB + r0 * BK + kofs;
        _Float16* lB1 = sB + (r0 + 16) * BK + kofs;

        for (int k0 = 0; k0 < 1024; k0 += BK) {
            gl_lds16(xh + a0o + k0, lA0);
            gl_lds16(xh + a1o + k0, lA1);
            gl_lds16(wvTh + b0o + k0, lB0);
            gl_lds16(wvTh + b1o + k0, lB1);
            __syncthreads();

            half8_t a0[4], b0[4];
#pragma unroll
            for (int mt = 0; mt < 4; ++mt)
                a0[mt] = *(const half8_t*)(sA + (wm + mt * 16 + lrow) * BK + quad * 8);
#pragma unroll
            for (int nt = 0; nt < 4; ++nt)
                b0[nt] = *(const half8_t*)(sB + (wn + nt * 16 + lrow) * BK + quad * 8);
#pragma unroll
            for (int mt = 0; mt < 4; ++mt)
#pragma unroll
                for (int nt = 0; nt < 4; ++nt)
                    acc[mt][nt] = __builtin_amdgcn_mfma_f32_16x16x32_f16(a0[mt], b0[nt], acc[mt][nt], 0, 0, 0);
            __syncthreads();
        }

        // epilogue: transpose through LDS -> coalesced vT writes.
        // tle[e_local][t_local], ldt = 132 (pad breaks 64-elem bank stride)
        _Float16* tle = (_Float16*)buf;
#pragma unroll
        for (int mt = 0; mt < 4; ++mt)
#pragma unroll
            for (int nt = 0; nt < 4; ++nt) {
                int t0 = wm + mt * 16 + quad * 4;
                int e_l = wn + nt * 16 + lrow;
                half4_t o;
#pragma unroll
                for (int r = 0; r < 4; ++r) o[r] = (_Float16)acc[mt][nt][r];
                *(half4_t*)(tle + e_l * 132 + t0) = o;
            }
        __syncthreads();
        const int b = bm >> 11, tb = bm & 2047;
#pragma unroll
        for (int i = 0; i < 8; ++i) {
            int flat = i * 256 + tid;
            int e_l = flat >> 4, c = (flat & 15) * 8;
            half4_t p0 = *(const half4_t*)(tle + e_l * 132 + c);
            half4_t p1 = *(const half4_t*)(tle + e_l * 132 + c + 4);
            half8_t o8;
            o8[0] = p0[0]; o8[1] = p0[1]; o8[2] = p0[2]; o8[3] = p0[3];
            o8[4] = p1[0]; o8[5] = p1[1]; o8[6] = p1[2]; o8[7] = p1[3];
            *(half8_t*)(vT + ((size_t)b << 21) + (size_t)(bn + e_l) * 2048 + tb + c) = o8;
        }
    }
}

// ---------------- plain-f16 GEMM (16x16x32), 128x128, 256 thr (round-3) ----------------
// A [M][K] f16, B [N][K] f16, write fp32 C row-major. Used for PV.
__global__ __launch_bounds__(256) void gemm_plain(
    const _Float16* __restrict__ Ag, size_t az,
    const _Float16* __restrict__ Bg, size_t bz,
    float* __restrict__ Cf, size_t cz, int ldc,
    int lda, int ldb, int K)
{
    __shared__ __align__(16) _Float16 sA[BM][BK], sB[BN][BK];

    const int tid = threadIdx.x;
    const int wave = tid >> 6, lane = tid & 63;
    const int wm = (wave >> 1) * 64, wn = (wave & 1) * 64;
    const int lrow = lane & 15, quad = lane >> 4;
    const int bm = blockIdx.y * BM, bn = blockIdx.x * BN;
    const int z = blockIdx.z;

    const _Float16* pA = Ag + (size_t)z * az;
    const _Float16* pB = Bg + (size_t)z * bz;

    const int r0 = wave * 32 + (lane >> 2);
    const int kofs = (lane & 3) * 8;
    const size_t a0o = (size_t)(bm + r0) * lda + kofs;
    const size_t a1o = a0o + (size_t)16 * lda;
    const size_t b0o = (size_t)(bn + r0) * ldb + kofs;
    const size_t b1o = b0o + (size_t)16 * ldb;
    _Float16* lA0 = &sA[r0][kofs];
    _Float16* lA1 = &sA[r0 + 16][kofs];
    _Float16* lB0 = &sB[r0][kofs];
    _Float16* lB1 = &sB[r0 + 16][kofs];

    f32x4 acc[4][4];
#pragma unroll
    for (int i = 0; i < 4; ++i)
#pragma unroll
        for (int j = 0; j < 4; ++j) acc[i][j] = 0.0f;

    for (int k0 = 0; k0 < K; k0 += BK) {
        gl_lds16(pA + a0o + k0, lA0);
        gl_lds16(pA + a1o + k0, lA1);
        gl_lds16(pB + b0o + k0, lB0);
        gl_lds16(pB + b1o + k0, lB1);
        __syncthreads();

        half8_t a0[4], b0[4];
#pragma unroll
        for (int mt = 0; mt < 4; ++mt)
            a0[mt] = *(const half8_t*)&sA[wm + mt * 16 + lrow][quad * 8];
#pragma unroll
        for (int nt = 0; nt < 4; ++nt)
            b0[nt] = *(const half8_t*)&sB[wn + nt * 16 + lrow][quad * 8];
#pragma unroll
        for (int mt = 0; mt < 4; ++mt)
#pragma unroll
            for (int nt = 0; nt < 4; ++nt)
                acc[mt][nt] = __builtin_amdgcn_mfma_f32_16x16x32_f16(a0[mt], b0[nt], acc[mt][nt], 0, 0, 0);
        __syncthreads();
    }

#pragma unroll
    for (int mt = 0; mt < 4; ++mt)
#pragma unroll
        for (int nt = 0; nt < 4; ++nt) {
            int gm0 = bm + wm + mt * 16 + quad * 4;
            int gn = bn + wn + nt * 16 + lrow;
#pragma unroll
            for (int r = 0; r < 4; ++r)
                Cf[(size_t)z * cz + (size_t)(gm0 + r) * ldc + gn] = acc[mt][nt][r];
        }
}

// ---------------- softmax: fp32 scores row -> f16 P row, in place ----------------
__global__ __launch_bounds__(256) void softmax_kernel(float* __restrict__ S)
{
    float* row = S + (size_t)blockIdx.x * 2048;
    float4* r4 = (float4*)row;
    const int tid = threadIdx.x;
    const int wave = tid >> 6, lane = tid & 63;

    float4 a = r4[tid], b = r4[tid + 256];
    float m = fmaxf(fmaxf(fmaxf(a.x, a.y), fmaxf(a.z, a.w)),
                    fmaxf(fmaxf(b.x, b.y), fmaxf(b.z, b.w)));
#pragma unroll
    for (int o = 32; o; o >>= 1) m = fmaxf(m, __shfl_xor(m, o));
    __shared__ float redm[4];
    __shared__ float reds[4];
    if (lane == 0) redm[wave] = m;
    __syncthreads();
    m = fmaxf(fmaxf(redm[0], redm[1]), fmaxf(redm[2], redm[3]));

    a.x = __expf(a.x - m); a.y = __expf(a.y - m);
    a.z = __expf(a.z - m); a.w = __expf(a.w - m);
    b.x = __expf(b.x - m); b.y = __expf(b.y - m);
    b.z = __expf(b.z - m); b.w = __expf(b.w - m);

    float s = a.x + a.y + a.z + a.w + b.x + b.y + b.z + b.w;
#pragma unroll
    for (int o = 32; o; o >>= 1) s += __shfl_xor(s, o);
    if (lane == 0) reds[wave] = s;
    __syncthreads();   // also orders all row loads before the f16 overwrite below
    s = reds[0] + reds[1] + reds[2] + reds[3];

    float inv = 1.0f / s;
    _Float16* o16 = (_Float16*)row;
    half4_t ha, hb;
    ha[0] = (_Float16)(a.x * inv); ha[1] = (_Float16)(a.y * inv);
    ha[2] = (_Float16)(a.z * inv); ha[3] = (_Float16)(a.w * inv);
    hb[0] = (_Float16)(b.x * inv); hb[1] = (_Float16)(b.y * inv);
    hb[2] = (_Float16)(b.z * inv); hb[3] = (_Float16)(b.w * inv);
    ((half4_t*)o16)[tid] = ha;
    ((half4_t*)o16)[tid + 256] = hb;
}

extern "C" void kernel_launch(void* const* d_in, const int* in_sizes, int n_in,
                              void* d_out, int out_size, void* d_ws, size_t ws_size,
                              hipStream_t stream)
{
    const float* x  = (const float*)d_in[0];
    const float* wq = (const float*)d_in[1];
    const float* wk = (const float*)d_in[2];
    const float* wv = (const float*)d_in[3];
    float* out = (float*)d_out;

    const int S = 2048, D = 1024;
    char* ws = (char*)d_ws;

    // ws layout (bytes); high-water 158 MB
    _Float16* xh   = (_Float16*)(ws);                  // 16 MB
    _Float16* xl   = (_Float16*)(ws + (16ull << 20));  // 16 MB
    _Float16* yh   = (_Float16*)(ws + (32ull << 20));  // 16 MB
    _Float16* yl   = (_Float16*)(ws + (48ull << 20));  // 16 MB
    _Float16* vT   = (_Float16*)(ws + (64ull << 20));  // 16 MB [4][1024][2048]
    _Float16* wqh  = (_Float16*)(ws + (80ull << 20));  // 2 MB (natural layout)
    _Float16* wql  = (_Float16*)(ws + (82ull << 20));  // 2 MB
    _Float16* wkh  = (_Float16*)(ws + (84ull << 20));  // 2 MB
    _Float16* wkl  = (_Float16*)(ws + (86ull << 20));  // 2 MB
    _Float16* wvTh = (_Float16*)(ws + (88ull << 20));  // 2 MB (transposed)
    _Float16* Mh   = (_Float16*)(ws + (90ull << 20));  // 2 MB  M' = Wk@Wq^T
    _Float16* Ml   = (_Float16*)(ws + (92ull << 20));  // 2 MB
    float*    sc   = (float*)(ws + (94ull << 20));     // 64 MB scores

    // 1) all conversions in one launch
    conv_all_kernel<<<dim3(8192, 4), dim3(256), 0, stream>>>(
        x, wq, wk, wv, xh, xl, wqh, wql, wkh, wkl, wvTh);

    // 2) M'[d'][d] = sum_e Wk[d',e]*Wq[d,e]  (split in, split out)
    gemm_split<false><<<dim3(D / BN, D / BM, 1), dim3(256), 0, stream>>>(
        wkh, wkl, 0, wqh, wql, 0, nullptr, 0, 0, Mh, Ml, 0, D, D, D, D);

    // 3) y-proj (split) + v-proj (plain, coalesced vT epilogue), one launch
    yv_kernel<<<dim3(D / BN, 8192 / BM, 2), dim3(256), 0, stream>>>(
        xh, xl, Mh, Ml, wvTh, yh, yl, vT);

    // 4) scores[b][s][t] = sum_d' y[b,s,d']*x[b,t,d']  (split), out fp32
    gemm_split<true><<<dim3(S / BN, S / BM, 4), dim3(256), 0, stream>>>(
        yh, yl, (size_t)S * D, xh, xl, (size_t)S * D, sc, (size_t)S * S, S,
        nullptr, nullptr, 0, 0, D, D, D);

    // 5) softmax rows, f16 P written in place (row stride stays 8192 B)
    softmax_kernel<<<dim3(4 * S), dim3(256), 0, stream>>>(sc);

    // 6) out = P @ v: A=P f16 (lda=4096 f16 elems), B=vT f16, out fp32
    gemm_plain<<<dim3(D / BN, S / BM, 4), dim3(256), 0, stream>>>(
        (const _Float16*)sc, (size_t)S * 4096, vT, (size_t)D * S,
        out, (size_t)S * D, D, 4096, S, S);
}

// Round 9
// 410.767 us; speedup vs baseline: 1.2002x; 1.0086x over previous
//
#include <hip/hip_runtime.h>

// AttentionBlock: x[4,2048,1024] fp32; scores = x@(Wq@Wk^T)@x^T (NO scale);
// softmax; out = P@(x@Wv).
// M' = Wk@Wq^T -> y = x@M'^T replaces both q,k projections; scores = y@x^T.
// Split-f16 (hi+lo, 3-MFMA) for M', y, scores; plain f16 for v, PV.
// Round 9 (r8 + store efficiency): (a) y-split epilogue round-trips through
// LDS -> coalesced 16B yh/yl writes (was 2B x 32 scattered per thread),
// (b) conv_all flat 1D grid (no 24K empty dispatches).
// Confirmed dead ends: 128x256 tiles (r4/r5), 32x32x16 MFMA (r6: bank
// conflicts 3x), direct-to-VGPR lo loads (r7), BK=64 (same aliasing as r6).

typedef _Float16 half4_t __attribute__((ext_vector_type(4)));
typedef _Float16 half8_t __attribute__((ext_vector_type(8)));
typedef float f32x4 __attribute__((ext_vector_type(4)));

#define BM 128
#define BN 128
#define BK 32

__device__ __forceinline__ void gl_lds16(const _Float16* g, _Float16* l) {
    __builtin_amdgcn_global_load_lds(
        (const __attribute__((address_space(1))) unsigned int*)g,
        (__attribute__((address_space(3))) unsigned int*)l, 16, 0, 0);
}

// ---------------- merged conversion kernel (flat 1D grid) ----------------
// blocks [0,8192): x split (2M float4); [8192,9216): wq split; [9216,10240):
// wk split; [10240,10496): wv -> wvT f16 hi (256 tiles of 64x64).
__global__ __launch_bounds__(256) void conv_all_kernel(
    const float* __restrict__ x, const float* __restrict__ wq,
    const float* __restrict__ wk, const float* __restrict__ wv,
    _Float16* __restrict__ xh, _Float16* __restrict__ xl,
    _Float16* __restrict__ qh, _Float16* __restrict__ ql,
    _Float16* __restrict__ kh, _Float16* __restrict__ kl,
    _Float16* __restrict__ vTh)
{
    __shared__ float tle[64][65];
    const int bid = blockIdx.x;
    if (bid < 10240) {
        const float* in;
        _Float16 *hi, *lo;
        int i0;
        if (bid < 8192)      { in = x;  hi = xh; lo = xl; i0 = bid; }
        else if (bid < 9216) { in = wq; hi = qh; lo = ql; i0 = bid - 8192; }
        else                 { in = wk; hi = kh; lo = kl; i0 = bid - 9216; }
        int i = i0 * 256 + threadIdx.x;
        float4 v = ((const float4*)in)[i];
        float xs[4] = {v.x, v.y, v.z, v.w};
        half4_t h, l;
#pragma unroll
        for (int j = 0; j < 4; ++j) {
            _Float16 hh = (_Float16)xs[j];
            h[j] = hh;
            l[j] = (_Float16)(xs[j] - (float)hh);
        }
        ((half4_t*)hi)[i] = h;
        ((half4_t*)lo)[i] = l;
    } else {
        const int t = bid - 10240;
        const int tr = (t >> 4) * 64, tc = (t & 15) * 64;
        const int t16 = threadIdx.x & 15, tq = threadIdx.x >> 4;
#pragma unroll
        for (int j = 0; j < 4; ++j) {
            int lr = tq + j * 16;
            float4 v = *(const float4*)(wv + (size_t)(tr + lr) * 1024 + tc + t16 * 4);
            tle[lr][t16 * 4 + 0] = v.x;
            tle[lr][t16 * 4 + 1] = v.y;
            tle[lr][t16 * 4 + 2] = v.z;
            tle[lr][t16 * 4 + 3] = v.w;
        }
        __syncthreads();
#pragma unroll
        for (int j = 0; j < 4; ++j) {
            int orow = tq + j * 16;
            int oc = t16 * 4;
            half4_t h;
#pragma unroll
            for (int i = 0; i < 4; ++i) h[i] = (_Float16)tle[oc + i][orow];
            *(half4_t*)(vTh + (size_t)(tc + orow) * 1024 + tr + oc) = h;
        }
    }
}

// ---------------- split-f16 GEMM (3-MFMA, 16x16x32), 128x128, 256 thr ----------------
// Round-3 exact. A planes [M][K], B planes [N][K] f16 (k-contiguous both).
// OUTF32: write fp32 C. else: write f16 hi/lo pair (element scatter — only
// used by the tiny M' GEMM where it doesn't matter).
template <bool OUTF32>
__global__ __launch_bounds__(256) void gemm_split(
    const _Float16* __restrict__ Ah, const _Float16* __restrict__ Al, size_t az,
    const _Float16* __restrict__ Bh, const _Float16* __restrict__ Bl, size_t bz,
    float* __restrict__ Cf, size_t cz, int ldc,
    _Float16* __restrict__ Oh, _Float16* __restrict__ Ol, size_t oz, int ldo,
    int lda, int ldb, int K)
{
    __shared__ __align__(16) _Float16 sAh[BM][BK], sAl[BM][BK];
    __shared__ __align__(16) _Float16 sBh[BN][BK], sBl[BN][BK];

    const int tid = threadIdx.x;
    const int wave = tid >> 6, lane = tid & 63;
    const int wm = (wave >> 1) * 64, wn = (wave & 1) * 64;
    const int lrow = lane & 15, quad = lane >> 4;
    const int bm = blockIdx.y * BM, bn = blockIdx.x * BN;
    const int z = blockIdx.z;

    const _Float16* pAh = Ah + (size_t)z * az;
    const _Float16* pAl = Al + (size_t)z * az;
    const _Float16* pBh = Bh + (size_t)z * bz;
    const _Float16* pBl = Bl + (size_t)z * bz;

    const int r0 = wave * 32 + (lane >> 2);
    const int kofs = (lane & 3) * 8;
    const size_t a0o = (size_t)(bm + r0) * lda + kofs;
    const size_t a1o = a0o + (size_t)16 * lda;
    const size_t b0o = (size_t)(bn + r0) * ldb + kofs;
    const size_t b1o = b0o + (size_t)16 * ldb;
    _Float16* lA0 = &sAh[r0][kofs];
    _Float16* lA1 = &sAh[r0 + 16][kofs];
    _Float16* lAl0 = &sAl[r0][kofs];
    _Float16* lAl1 = &sAl[r0 + 16][kofs];
    _Float16* lB0 = &sBh[r0][kofs];
    _Float16* lB1 = &sBh[r0 + 16][kofs];
    _Float16* lBl0 = &sBl[r0][kofs];
    _Float16* lBl1 = &sBl[r0 + 16][kofs];

    f32x4 acc[4][4];
#pragma unroll
    for (int i = 0; i < 4; ++i)
#pragma unroll
        for (int j = 0; j < 4; ++j) acc[i][j] = 0.0f;

    for (int k0 = 0; k0 < K; k0 += BK) {
        gl_lds16(pAh + a0o + k0, lA0);
        gl_lds16(pAh + a1o + k0, lA1);
        gl_lds16(pAl + a0o + k0, lAl0);
        gl_lds16(pAl + a1o + k0, lAl1);
        gl_lds16(pBh + b0o + k0, lB0);
        gl_lds16(pBh + b1o + k0, lB1);
        gl_lds16(pBl + b0o + k0, lBl0);
        gl_lds16(pBl + b1o + k0, lBl1);
        __syncthreads();

        half8_t a0[4], a1[4], b0[4], b1[4];
#pragma unroll
        for (int mt = 0; mt < 4; ++mt) {
            a0[mt] = *(const half8_t*)&sAh[wm + mt * 16 + lrow][quad * 8];
            a1[mt] = *(const half8_t*)&sAl[wm + mt * 16 + lrow][quad * 8];
        }
#pragma unroll
        for (int nt = 0; nt < 4; ++nt) {
            b0[nt] = *(const half8_t*)&sBh[wn + nt * 16 + lrow][quad * 8];
            b1[nt] = *(const half8_t*)&sBl[wn + nt * 16 + lrow][quad * 8];
        }
#pragma unroll
        for (int mt = 0; mt < 4; ++mt)
#pragma unroll
            for (int nt = 0; nt < 4; ++nt) {
                acc[mt][nt] = __builtin_amdgcn_mfma_f32_16x16x32_f16(a0[mt], b0[nt], acc[mt][nt], 0, 0, 0);
                acc[mt][nt] = __builtin_amdgcn_mfma_f32_16x16x32_f16(a0[mt], b1[nt], acc[mt][nt], 0, 0, 0);
                acc[mt][nt] = __builtin_amdgcn_mfma_f32_16x16x32_f16(a1[mt], b0[nt], acc[mt][nt], 0, 0, 0);
            }
        __syncthreads();
    }

#pragma unroll
    for (int mt = 0; mt < 4; ++mt)
#pragma unroll
        for (int nt = 0; nt < 4; ++nt)
#pragma unroll
            for (int r = 0; r < 4; ++r) {
                int gm = bm + wm + mt * 16 + quad * 4 + r;
                int gn = bn + wn + nt * 16 + lrow;
                float v = acc[mt][nt][r];
                if (OUTF32) {
                    Cf[(size_t)z * cz + (size_t)gm * ldc + gn] = v;
                } else {
                    _Float16 h = (_Float16)v;
                    Oh[(size_t)z * oz + (size_t)gm * ldo + gn] = h;
                    Ol[(size_t)z * oz + (size_t)gm * ldo + gn] = (_Float16)(v - (float)h);
                }
            }
}

// ---------------- merged y-proj (split) + v-proj (plain) kernel ----------------
// role = blockIdx.z. role 0: y = x@M'^T, split-out to yh/yl, coalesced via LDS
// transpose. role 1: v = x@wvT^T, plain f16, vT[b][e][t] coalesced via LDS.
// Fixed K=1024, ld*=1024.
__global__ __launch_bounds__(256) void yv_kernel(
    const _Float16* __restrict__ xh, const _Float16* __restrict__ xl,
    const _Float16* __restrict__ Mh, const _Float16* __restrict__ Ml,
    const _Float16* __restrict__ wvTh,
    _Float16* __restrict__ yh, _Float16* __restrict__ yl,
    _Float16* __restrict__ vT)
{
    __shared__ __align__(16) char buf[128 * 132 * 2];  // 33792 B

    const int tid = threadIdx.x;
    const int wave = tid >> 6, lane = tid & 63;
    const int wm = (wave >> 1) * 64, wn = (wave & 1) * 64;
    const int lrow = lane & 15, quad = lane >> 4;
    const int bm = blockIdx.y * BM, bn = blockIdx.x * BN;
    const bool vrole = (blockIdx.z != 0);

    const int r0 = wave * 32 + (lane >> 2);
    const int kofs = (lane & 3) * 8;
    const size_t a0o = (size_t)(bm + r0) * 1024 + kofs;
    const size_t a1o = a0o + (size_t)16 * 1024;
    const size_t b0o = (size_t)(bn + r0) * 1024 + kofs;
    const size_t b1o = b0o + (size_t)16 * 1024;

    f32x4 acc[4][4];
#pragma unroll
    for (int i = 0; i < 4; ++i)
#pragma unroll
        for (int j = 0; j < 4; ++j) acc[i][j] = 0.0f;

    _Float16* tle = (_Float16*)buf;  // [128][132] f16 for epilogue transposes

    if (!vrole) {
        // ---- split path: A = xh/xl, B = Mh/Ml
        _Float16* sAh = (_Float16*)buf;               // [128][32]
        _Float16* sAl = (_Float16*)(buf + 8192);
        _Float16* sBh = (_Float16*)(buf + 16384);
        _Float16* sBl = (_Float16*)(buf + 24576);
        _Float16* lA0 = sAh + r0 * BK + kofs;
        _Float16* lA1 = sAh + (r0 + 16) * BK + kofs;
        _Float16* lAl0 = sAl + r0 * BK + kofs;
        _Float16* lAl1 = sAl + (r0 + 16) * BK + kofs;
        _Float16* lB0 = sBh + r0 * BK + kofs;
        _Float16* lB1 = sBh + (r0 + 16) * BK + kofs;
        _Float16* lBl0 = sBl + r0 * BK + kofs;
        _Float16* lBl1 = sBl + (r0 + 16) * BK + kofs;

        for (int k0 = 0; k0 < 1024; k0 += BK) {
            gl_lds16(xh + a0o + k0, lA0);
            gl_lds16(xh + a1o + k0, lA1);
            gl_lds16(xl + a0o + k0, lAl0);
            gl_lds16(xl + a1o + k0, lAl1);
            gl_lds16(Mh + b0o + k0, lB0);
            gl_lds16(Mh + b1o + k0, lB1);
            gl_lds16(Ml + b0o + k0, lBl0);
            gl_lds16(Ml + b1o + k0, lBl1);
            __syncthreads();

            half8_t a0[4], a1[4], b0[4], b1[4];
#pragma unroll
            for (int mt = 0; mt < 4; ++mt) {
                a0[mt] = *(const half8_t*)(sAh + (wm + mt * 16 + lrow) * BK + quad * 8);
                a1[mt] = *(const half8_t*)(sAl + (wm + mt * 16 + lrow) * BK + quad * 8);
            }
#pragma unroll
            for (int nt = 0; nt < 4; ++nt) {
                b0[nt] = *(const half8_t*)(sBh + (wn + nt * 16 + lrow) * BK + quad * 8);
                b1[nt] = *(const half8_t*)(sBl + (wn + nt * 16 + lrow) * BK + quad * 8);
            }
#pragma unroll
            for (int mt = 0; mt < 4; ++mt)
#pragma unroll
                for (int nt = 0; nt < 4; ++nt) {
                    acc[mt][nt] = __builtin_amdgcn_mfma_f32_16x16x32_f16(a0[mt], b0[nt], acc[mt][nt], 0, 0, 0);
                    acc[mt][nt] = __builtin_amdgcn_mfma_f32_16x16x32_f16(a0[mt], b1[nt], acc[mt][nt], 0, 0, 0);
                    acc[mt][nt] = __builtin_amdgcn_mfma_f32_16x16x32_f16(a1[mt], b0[nt], acc[mt][nt], 0, 0, 0);
                }
            __syncthreads();
        }

        // epilogue: two LDS round-trips -> coalesced 16B yh then yl writes.
        // pass 0: hi plane; pass 1: lo plane (recomputed from acc).
#pragma unroll
        for (int pass = 0; pass < 2; ++pass) {
            if (pass) __syncthreads();
#pragma unroll
            for (int mt = 0; mt < 4; ++mt)
#pragma unroll
                for (int nt = 0; nt < 4; ++nt) {
                    int rloc = wm + mt * 16 + quad * 4;
                    int cloc = wn + nt * 16 + lrow;
#pragma unroll
                    for (int r = 0; r < 4; ++r) {
                        float v = acc[mt][nt][r];
                        _Float16 h = (_Float16)v;
                        tle[(rloc + r) * 132 + cloc] =
                            pass == 0 ? h : (_Float16)(v - (float)h);
                    }
                }
            __syncthreads();
            _Float16* dst = pass == 0 ? yh : yl;
#pragma unroll
            for (int i = 0; i < 8; ++i) {
                int flat = i * 256 + tid;
                int rloc = flat >> 4, c = (flat & 15) * 8;
                half8_t o8;
#pragma unroll
                for (int j = 0; j < 8; ++j) o8[j] = tle[rloc * 132 + c + j];
                *(half8_t*)(dst + (size_t)(bm + rloc) * 1024 + bn + c) = o8;
            }
        }
    } else {
        // ---- plain path: A = xh, B = wvTh
        _Float16* sA = (_Float16*)buf;     // [128][32]
        _Float16* sB = (_Float16*)(buf + 8192);
        _Float16* lA0 = sA + r0 * BK + kofs;
        _Float16* lA1 = sA + (r0 + 16) * BK + kofs;
        _Float16* lB0 = sB + r0 * BK + kofs;
        _Float16* lB1 = sB + (r0 + 16) * BK + kofs;

        for (int k0 = 0; k0 < 1024; k0 += BK) {
            gl_lds16(xh + a0o + k0, lA0);
            gl_lds16(xh + a1o + k0, lA1);
            gl_lds16(wvTh + b0o + k0, lB0);
            gl_lds16(wvTh + b1o + k0, lB1);
            __syncthreads();

            half8_t a0[4], b0[4];
#pragma unroll
            for (int mt = 0; mt < 4; ++mt)
                a0[mt] = *(const half8_t*)(sA + (wm + mt * 16 + lrow) * BK + quad * 8);
#pragma unroll
            for (int nt = 0; nt < 4; ++nt)
                b0[nt] = *(const half8_t*)(sB + (wn + nt * 16 + lrow) * BK + quad * 8);
#pragma unroll
            for (int mt = 0; mt < 4; ++mt)
#pragma unroll
                for (int nt = 0; nt < 4; ++nt)
                    acc[mt][nt] = __builtin_amdgcn_mfma_f32_16x16x32_f16(a0[mt], b0[nt], acc[mt][nt], 0, 0, 0);
            __syncthreads();
        }

        // epilogue: transpose through LDS -> coalesced vT writes.
        // tle[e_local][t_local], ldt = 132
#pragma unroll
        for (int mt = 0; mt < 4; ++mt)
#pragma unroll
            for (int nt = 0; nt < 4; ++nt) {
                int t0 = wm + mt * 16 + quad * 4;
                int e_l = wn + nt * 16 + lrow;
                half4_t o;
#pragma unroll
                for (int r = 0; r < 4; ++r) o[r] = (_Float16)acc[mt][nt][r];
                *(half4_t*)(tle + e_l * 132 + t0) = o;
            }
        __syncthreads();
        const int b = bm >> 11, tb = bm & 2047;
#pragma unroll
        for (int i = 0; i < 8; ++i) {
            int flat = i * 256 + tid;
            int e_l = flat >> 4, c = (flat & 15) * 8;
            half8_t o8;
#pragma unroll
            for (int j = 0; j < 8; ++j) o8[j] = tle[e_l * 132 + c + j];
            *(half8_t*)(vT + ((size_t)b << 21) + (size_t)(bn + e_l) * 2048 + tb + c) = o8;
        }
    }
}

// ---------------- plain-f16 GEMM (16x16x32), 128x128, 256 thr (PV) ----------------
// A [M][K] f16, B [N][K] f16, write fp32 C row-major.
__global__ __launch_bounds__(256) void gemm_plain(
    const _Float16* __restrict__ Ag, size_t az,
    const _Float16* __restrict__ Bg, size_t bz,
    float* __restrict__ Cf, size_t cz, int ldc,
    int lda, int ldb, int K)
{
    __shared__ __align__(16) _Float16 sA[BM][BK], sB[BN][BK];

    const int tid = threadIdx.x;
    const int wave = tid >> 6, lane = tid & 63;
    const int wm = (wave >> 1) * 64, wn = (wave & 1) * 64;
    const int lrow = lane & 15, quad = lane >> 4;
    const int bm = blockIdx.y * BM, bn = blockIdx.x * BN;
    const int z = blockIdx.z;

    const _Float16* pA = Ag + (size_t)z * az;
    const _Float16* pB = Bg + (size_t)z * bz;

    const int r0 = wave * 32 + (lane >> 2);
    const int kofs = (lane & 3) * 8;
    const size_t a0o = (size_t)(bm + r0) * lda + kofs;
    const size_t a1o = a0o + (size_t)16 * lda;
    const size_t b0o = (size_t)(bn + r0) * ldb + kofs;
    const size_t b1o = b0o + (size_t)16 * ldb;
    _Float16* lA0 = &sA[r0][kofs];
    _Float16* lA1 = &sA[r0 + 16][kofs];
    _Float16* lB0 = &sB[r0][kofs];
    _Float16* lB1 = &sB[r0 + 16][kofs];

    f32x4 acc[4][4];
#pragma unroll
    for (int i = 0; i < 4; ++i)
#pragma unroll
        for (int j = 0; j < 4; ++j) acc[i][j] = 0.0f;

    for (int k0 = 0; k0 < K; k0 += BK) {
        gl_lds16(pA + a0o + k0, lA0);
        gl_lds16(pA + a1o + k0, lA1);
        gl_lds16(pB + b0o + k0, lB0);
        gl_lds16(pB + b1o + k0, lB1);
        __syncthreads();

        half8_t a0[4], b0[4];
#pragma unroll
        for (int mt = 0; mt < 4; ++mt)
            a0[mt] = *(const half8_t*)&sA[wm + mt * 16 + lrow][quad * 8];
#pragma unroll
        for (int nt = 0; nt < 4; ++nt)
            b0[nt] = *(const half8_t*)&sB[wn + nt * 16 + lrow][quad * 8];
#pragma unroll
        for (int mt = 0; mt < 4; ++mt)
#pragma unroll
            for (int nt = 0; nt < 4; ++nt)
                acc[mt][nt] = __builtin_amdgcn_mfma_f32_16x16x32_f16(a0[mt], b0[nt], acc[mt][nt], 0, 0, 0);
        __syncthreads();
    }

#pragma unroll
    for (int mt = 0; mt < 4; ++mt)
#pragma unroll
        for (int nt = 0; nt < 4; ++nt) {
            int gm0 = bm + wm + mt * 16 + quad * 4;
            int gn = bn + wn + nt * 16 + lrow;
#pragma unroll
            for (int r = 0; r < 4; ++r)
                Cf[(size_t)z * cz + (size_t)(gm0 + r) * ldc + gn] = acc[mt][nt][r];
        }
}

// ---------------- softmax: fp32 scores row -> f16 P row, in place ----------------
__global__ __launch_bounds__(256) void softmax_kernel(float* __restrict__ S)
{
    float* row = S + (size_t)blockIdx.x * 2048;
    float4* r4 = (float4*)row;
    const int tid = threadIdx.x;
    const int wave = tid >> 6, lane = tid & 63;

    float4 a = r4[tid], b = r4[tid + 256];
    float m = fmaxf(fmaxf(fmaxf(a.x, a.y), fmaxf(a.z, a.w)),
                    fmaxf(fmaxf(b.x, b.y), fmaxf(b.z, b.w)));
#pragma unroll
    for (int o = 32; o; o >>= 1) m = fmaxf(m, __shfl_xor(m, o));
    __shared__ float redm[4];
    __shared__ float reds[4];
    if (lane == 0) redm[wave] = m;
    __syncthreads();
    m = fmaxf(fmaxf(redm[0], redm[1]), fmaxf(redm[2], redm[3]));

    a.x = __expf(a.x - m); a.y = __expf(a.y - m);
    a.z = __expf(a.z - m); a.w = __expf(a.w - m);
    b.x = __expf(b.x - m); b.y = __expf(b.y - m);
    b.z = __expf(b.z - m); b.w = __expf(b.w - m);

    float s = a.x + a.y + a.z + a.w + b.x + b.y + b.z + b.w;
#pragma unroll
    for (int o = 32; o; o >>= 1) s += __shfl_xor(s, o);
    if (lane == 0) reds[wave] = s;
    __syncthreads();   // also orders all row loads before the f16 overwrite below
    s = reds[0] + reds[1] + reds[2] + reds[3];

    float inv = 1.0f / s;
    _Float16* o16 = (_Float16*)row;
    half4_t ha, hb;
    ha[0] = (_Float16)(a.x * inv); ha[1] = (_Float16)(a.y * inv);
    ha[2] = (_Float16)(a.z * inv); ha[3] = (_Float16)(a.w * inv);
    hb[0] = (_Float16)(b.x * inv); hb[1] = (_Float16)(b.y * inv);
    hb[2] = (_Float16)(b.z * inv); hb[3] = (_Float16)(b.w * inv);
    ((half4_t*)o16)[tid] = ha;
    ((half4_t*)o16)[tid + 256] = hb;
}

extern "C" void kernel_launch(void* const* d_in, const int* in_sizes, int n_in,
                              void* d_out, int out_size, void* d_ws, size_t ws_size,
                              hipStream_t stream)
{
    const float* x  = (const float*)d_in[0];
    const float* wq = (const float*)d_in[1];
    const float* wk = (const float*)d_in[2];
    const float* wv = (const float*)d_in[3];
    float* out = (float*)d_out;

    const int S = 2048, D = 1024;
    char* ws = (char*)d_ws;

    // ws layout (bytes); high-water 158 MB
    _Float16* xh   = (_Float16*)(ws);                  // 16 MB
    _Float16* xl   = (_Float16*)(ws + (16ull << 20));  // 16 MB
    _Float16* yh   = (_Float16*)(ws + (32ull << 20));  // 16 MB
    _Float16* yl   = (_Float16*)(ws + (48ull << 20));  // 16 MB
    _Float16* vT   = (_Float16*)(ws + (64ull << 20));  // 16 MB [4][1024][2048]
    _Float16* wqh  = (_Float16*)(ws + (80ull << 20));  // 2 MB (natural layout)
    _Float16* wql  = (_Float16*)(ws + (82ull << 20));  // 2 MB
    _Float16* wkh  = (_Float16*)(ws + (84ull << 20));  // 2 MB
    _Float16* wkl  = (_Float16*)(ws + (86ull << 20));  // 2 MB
    _Float16* wvTh = (_Float16*)(ws + (88ull << 20));  // 2 MB (transposed)
    _Float16* Mh   = (_Float16*)(ws + (90ull << 20));  // 2 MB  M' = Wk@Wq^T
    _Float16* Ml   = (_Float16*)(ws + (92ull << 20));  // 2 MB
    float*    sc   = (float*)(ws + (94ull << 20));     // 64 MB scores

    // 1) all conversions, flat grid
    conv_all_kernel<<<dim3(10496), dim3(256), 0, stream>>>(
        x, wq, wk, wv, xh, xl, wqh, wql, wkh, wkl, wvTh);

    // 2) M'[d'][d] = sum_e Wk[d',e]*Wq[d,e]  (split in, split out)
    gemm_split<false><<<dim3(D / BN, D / BM, 1), dim3(256), 0, stream>>>(
        wkh, wkl, 0, wqh, wql, 0, nullptr, 0, 0, Mh, Ml, 0, D, D, D, D);

    // 3) y-proj (split, coalesced epilogue) + v-proj (plain, coalesced vT)
    yv_kernel<<<dim3(D / BN, 8192 / BM, 2), dim3(256), 0, stream>>>(
        xh, xl, Mh, Ml, wvTh, yh, yl, vT);

    // 4) scores[b][s][t] = sum_d' y[b,s,d']*x[b,t,d']  (split), out fp32
    gemm_split<true><<<dim3(S / BN, S / BM, 4), dim3(256), 0, stream>>>(
        yh, yl, (size_t)S * D, xh, xl, (size_t)S * D, sc, (size_t)S * S, S,
        nullptr, nullptr, 0, 0, D, D, D);

    // 5) softmax rows, f16 P written in place (row stride stays 8192 B)
    softmax_kernel<<<dim3(4 * S), dim3(256), 0, stream>>>(sc);

    // 6) out = P @ v: A=P f16 (lda=4096 f16 elems), B=vT f16, out fp32
    gemm_plain<<<dim3(D / BN, S / BM, 4), dim3(256), 0, stream>>>(
        (const _Float16*)sc, (size_t)S * 4096, vT, (size_t)D * S,
        out, (size_t)S * D, D, 4096, S, S);
}